// Round 4
// baseline (1389.898 us; speedup 1.0000x reference)
//
#include <hip/hip_runtime.h>
#include <hip/hip_bf16.h>
#include <math.h>

#define NN 2048
#define TT 32
#define DD 256
#define HH 8
#define KK 32
#define EE 8192
#define ROWS (NN*TT)    // 65536
#define HS 2            // heads per pass
#define PS2 320         // P row stride: [Aq|Bq|Ak|Bk|V] x (HS*32) cols

typedef short s8v __attribute__((ext_vector_type(8)));
typedef float f4v __attribute__((ext_vector_type(4)));

typedef __attribute__((address_space(3))) unsigned char lds_t;
typedef __attribute__((address_space(1))) const unsigned char glob_t;
__device__ __forceinline__ void glds16(const void* g, void* l){
  __builtin_amdgcn_global_load_lds((glob_t*)g, (lds_t*)l, 16, 0, 0);
}

__device__ __forceinline__ float bfu2f(unsigned short u){
  return __uint_as_float(((unsigned int)u)<<16);
}
__device__ __forceinline__ unsigned short f2bfu(float f){
  __hip_bfloat16 h = __float2bfloat16(f);
  return *reinterpret_cast<unsigned short*>(&h);
}
__device__ __forceinline__ void ld8bf(const unsigned short* p, float* o){
  uint4 u = *reinterpret_cast<const uint4*>(p);
  const unsigned short* us = reinterpret_cast<const unsigned short*>(&u);
#pragma unroll
  for(int i=0;i<8;i++) o[i] = bfu2f(us[i]);
}
__device__ __forceinline__ uint4 ld16(const unsigned short* p){
  return *reinterpret_cast<const uint4*>(p);
}
// raw bf16x8 + fp32 bias fragment -> bf16 fragment
__device__ __forceinline__ s8v addpack(uint4 raw, const float* B){
  const unsigned short* us = reinterpret_cast<const unsigned short*>(&raw);
  s8v r;
#pragma unroll
  for(int j=0;j<8;j++) r[j] = (short)f2bfu(bfu2f(us[j]) + B[j]);
  return r;
}

// ---------------- CSR build ----------------
__global__ void k_zero_i32(int* p, int n){
  int i = blockIdx.x*256 + threadIdx.x;
  if(i<n) p[i]=0;
}
__global__ void k_zero_f4(float4* p, int n4){
  int i = blockIdx.x*256 + threadIdx.x;
  if(i<n4) p[i] = make_float4(0.f,0.f,0.f,0.f);
}
__global__ void k_hist(const int* __restrict__ recv, int* __restrict__ deg){
  int e = blockIdx.x*256 + threadIdx.x;
  if(e<EE) atomicAdd(&deg[recv[e]], 1);
}
__global__ void k_scan(const int* __restrict__ deg, int* __restrict__ offs, int* __restrict__ cursor){
  __shared__ int buf[2][NN];
  int tid = threadIdx.x;
  for(int i=tid;i<NN;i+=256) buf[0][i] = deg[i];
  __syncthreads();
  int src = 0;
  for(int off=1; off<NN; off<<=1){
    for(int i=tid;i<NN;i+=256){
      int v = buf[src][i];
      if(i>=off) v += buf[src][i-off];
      buf[1-src][i] = v;
    }
    src = 1-src;
    __syncthreads();
  }
  for(int i=tid;i<NN;i+=256){
    int ex = (i==0)?0:buf[src][i-1];
    offs[i]=ex; cursor[i]=ex;
  }
  if(tid==0) offs[NN]=EE;
}
__global__ void k_scatter(const int* __restrict__ recv, int* __restrict__ cursor, int* __restrict__ elist){
  int e = blockIdx.x*256 + threadIdx.x;
  if(e<EE){
    int pos = atomicAdd(&cursor[recv[e]], 1);
    elist[pos] = e;
  }
}

// ---------------- LayerNorm: fp32 in -> bf16 out ----------------
__global__ __launch_bounds__(256) void k_ln_f2b(const float* __restrict__ x,
    const float* __restrict__ sc, const float* __restrict__ of,
    unsigned short* __restrict__ out){
  int gw = (blockIdx.x*256 + threadIdx.x)>>6;
  int lane = threadIdx.x & 63;
  size_t base = (size_t)gw*DD + lane*4;
  float4 xv = *reinterpret_cast<const float4*>(x + base);
  float v[4] = {xv.x, xv.y, xv.z, xv.w};
  float s = v[0]+v[1]+v[2]+v[3];
  float q = v[0]*v[0]+v[1]*v[1]+v[2]*v[2]+v[3]*v[3];
#pragma unroll
  for(int o=32;o>0;o>>=1){ s += __shfl_xor(s,o); q += __shfl_xor(q,o); }
  float mean = s*(1.0f/DD);
  float var = q*(1.0f/DD) - mean*mean;
  float rs = rsqrtf(var + 1e-5f);
  float4 scv = *reinterpret_cast<const float4*>(sc + lane*4);
  float4 ofv = *reinterpret_cast<const float4*>(of + lane*4);
  ushort4 o4;
  o4.x = f2bfu((v[0]-mean)*rs*scv.x+ofv.x);
  o4.y = f2bfu((v[1]-mean)*rs*scv.y+ofv.y);
  o4.z = f2bfu((v[2]-mean)*rs*scv.z+ofv.z);
  o4.w = f2bfu((v[3]-mean)*rs*scv.w+ofv.w);
  *reinterpret_cast<ushort4*>(out + base) = o4;
}

// out = LN(nodes + attn_total), fp32 out   (attn buffer already includes D2)
__global__ __launch_bounds__(256) void k_final(
    const float* __restrict__ nodes, const float* __restrict__ attn,
    const float* __restrict__ sc, const float* __restrict__ of,
    float* __restrict__ out){
  int gw = (blockIdx.x*256 + threadIdx.x)>>6;
  int lane = threadIdx.x & 63;
  size_t base = (size_t)gw*DD + lane*4;
  float4 a4 = *reinterpret_cast<const float4*>(nodes + base);
  float4 c4 = *reinterpret_cast<const float4*>(attn + base);
  float v[4];
  v[0]=a4.x+c4.x; v[1]=a4.y+c4.y; v[2]=a4.z+c4.z; v[3]=a4.w+c4.w;
  float s = v[0]+v[1]+v[2]+v[3];
  float q = v[0]*v[0]+v[1]*v[1]+v[2]*v[2]+v[3]*v[3];
#pragma unroll
  for(int o=32;o>0;o>>=1){ s += __shfl_xor(s,o); q += __shfl_xor(q,o); }
  float mean = s*(1.0f/DD);
  float var = q*(1.0f/DD) - mean*mean;
  float rs = rsqrtf(var + 1e-5f);
  float4 scv = *reinterpret_cast<const float4*>(sc + lane*4);
  float4 ofv = *reinterpret_cast<const float4*>(of + lane*4);
  float4 o4;
  o4.x = (v[0]-mean)*rs*scv.x+ofv.x;
  o4.y = (v[1]-mean)*rs*scv.y+ofv.y;
  o4.z = (v[2]-mean)*rs*scv.z+ofv.z;
  o4.w = (v[3]-mean)*rs*scv.w+ofv.w;
  *reinterpret_cast<float4*>(out + base) = o4;
}

// ---------------- Weight transpose + fp32->bf16: in[R][C] f32 -> out[C][R] bf16 ----------------
__global__ void k_transpose(const float* __restrict__ in, unsigned short* __restrict__ out,
                            int R, int C){
  __shared__ unsigned short tile[32][33];
  int c0 = blockIdx.x*32, r0 = blockIdx.y*32;
  int tx = threadIdx.x & 31, ty = threadIdx.x >> 5;
  for(int i=ty;i<32;i+=8){
    int r = r0+i, c = c0+tx;
    tile[i][tx] = (r<R && c<C) ? f2bfu(in[(size_t)r*C + c]) : (unsigned short)0;
  }
  __syncthreads();
  for(int i=ty;i<32;i+=8){
    int c = c0+i, r = r0+tx;
    if(c<C && r<R) out[(size_t)c*R + r] = tile[tx][i];
  }
}

// ---------------- Build fused per-pass projection weights ----------------
__global__ void k_buildw(const float* __restrict__ Wq, const float* __restrict__ Wk,
                         const float* __restrict__ Wv,
                         const float* __restrict__ bq, const float* __restrict__ bk,
                         const float* __restrict__ bv,
                         unsigned short* __restrict__ WTall, float* __restrict__ biasall){
  int bx = blockIdx.x;            // p*320 + c
  int p = bx/320, c = bx - p*320;
  int k = threadIdx.x;
  int g = c>>6, hh = (c>>5)&1, j = c&31;
  int h = p*HS + hh;
  int col = h*32 + j;
  float w;
  if(g==0)      w = Wq[(size_t)k*256 + col];
  else if(g==1) w = Wq[(size_t)(256+k)*256 + col];
  else if(g==2) w = Wk[(size_t)k*256 + col];
  else if(g==3) w = Wk[(size_t)(256+k)*256 + col];
  else          w = Wv[(size_t)k*256 + col];
  WTall[((size_t)bx)*256 + k] = f2bfu(w);
  if(k==0){
    float b = 0.f;
    if(g==0) b = bq[col];
    else if(g==2) b = bk[col];
    else if(g==4) b = bv[col];
    biasall[bx] = b;
  }
}

// ---------------- Projection GEMM: P2[ROWS][320] = nnorm @ WTall_p^T + bias ----------------
__global__ __launch_bounds__(256) void k_projg(
    const unsigned short* __restrict__ A,      // [ROWS][256]
    const unsigned short* __restrict__ Bt,     // [320][256] for this pass
    const float* __restrict__ bias,            // [320]
    unsigned short* __restrict__ P){
  __shared__ unsigned short Asm[128*32];
  __shared__ unsigned short Bsm[64*32];
  int tid = threadIdx.x, lane = tid&63;
  int wid = tid>>6;
  int wrow = (wid>>1)*64, wcol = (wid&1)*32;
  int m0 = blockIdx.x*128, n0 = blockIdx.y*64;
  f4v acc[4][2];
#pragma unroll
  for(int mi=0;mi<4;mi++)
#pragma unroll
    for(int ni=0;ni<2;ni++) acc[mi][ni] = (f4v){0.f,0.f,0.f,0.f};
  int q = lane>>4, l16 = lane&15;
  int ra0 = tid>>2, ca0 = (tid&3)*8;
  int c1 = tid+256, ra1 = c1>>2, ca1 = (c1&3)*8;
  for(int k0=0;k0<256;k0+=32){
    glds16(A + (size_t)(m0+ra0)*256 + k0 + ca0, &Asm[tid*8]);
    glds16(A + (size_t)(m0+ra1)*256 + k0 + ca1, &Asm[c1*8]);
    glds16(Bt + (size_t)(n0+ra0)*256 + k0 + ca0, &Bsm[tid*8]);
    __syncthreads();
    s8v af[4], bfr[2];
#pragma unroll
    for(int mi=0;mi<4;mi++) af[mi]  = *reinterpret_cast<const s8v*>(&Asm[(wrow+mi*16+l16)*32 + q*8]);
#pragma unroll
    for(int ni=0;ni<2;ni++) bfr[ni] = *reinterpret_cast<const s8v*>(&Bsm[(wcol+ni*16+l16)*32 + q*8]);
#pragma unroll
    for(int mi=0;mi<4;mi++)
#pragma unroll
      for(int ni=0;ni<2;ni++)
        acc[mi][ni] = __builtin_amdgcn_mfma_f32_16x16x32_bf16(af[mi], bfr[ni], acc[mi][ni], 0, 0, 0);
    __syncthreads();
  }
#pragma unroll
  for(int mi=0;mi<4;mi++)
#pragma unroll
    for(int ni=0;ni<2;ni++){
      int ccol = n0 + wcol + ni*16 + l16;
      float bvv = bias[ccol];
#pragma unroll
      for(int r=0;r<4;r++){
        int crow = m0 + wrow + mi*16 + q*4 + r;
        P[(size_t)crow*PS2 + ccol] = f2bfu(acc[mi][ni][r] + bvv);
      }
    }
}

// ---------------- Attention phase 1: edge-parallel denominator accumulation ----------------
// One 64-thread block (one wave) per (edge, head). LDS-free: Q/K MFMA fragments are loaded
// directly from P rows (fragment layout row=l16, k=q*8+j is a contiguous 16B slice), receiver
// bias fragments hoisted and added in registers. D[n][hh][row][col] += exp(logit) over causal
// positions; masked positions form their own uniform softmax handled in k_attn_pv.
__global__ __launch_bounds__(64) void k_attn_stats(
    const unsigned short* __restrict__ P,
    const float* __restrict__ alibi,
    const int* __restrict__ receivers, const int* __restrict__ senders,
    float* __restrict__ Dbuf, int h0){
  int lane = threadIdx.x;
  int g = blockIdx.x;               // [0, EE*HS)
  int e = g>>1, hh = g&1, h = h0+hh;
  int q = lane>>4, l16 = lane&15;
  const float rsK = 0.17677669529663687f;   // 1/sqrt(32)

  int n = receivers[e], s = senders[e];
  size_t nb = (size_t)n*TT*PS2 + hh*32 + q*8;
  size_t sb = (size_t)s*TT*PS2 + hh*32 + q*8;

  // sender fragments (raw) — issue early
  uint4 rA0 = ld16(P + sb + (size_t)l16*PS2);
  uint4 rA1 = ld16(P + sb + (size_t)(16+l16)*PS2);
  uint4 rK0 = ld16(P + sb + 128 + (size_t)l16*PS2);
  uint4 rK1 = ld16(P + sb + 128 + (size_t)(16+l16)*PS2);
  // receiver bias fragments
  float BqF0[8], BqF1[8], BkF0[8], BkF1[8];
  ld8bf(P + nb + 64  + (size_t)l16*PS2,      BqF0);
  ld8bf(P + nb + 64  + (size_t)(16+l16)*PS2, BqF1);
  ld8bf(P + nb + 192 + (size_t)l16*PS2,      BkF0);
  ld8bf(P + nb + 192 + (size_t)(16+l16)*PS2, BkF1);

  s8v aq0 = addpack(rA0, BqF0), aq1 = addpack(rA1, BqF1);
  s8v bk0 = addpack(rK0, BkF0), bk1 = addpack(rK1, BkF1);
  f4v zero = (f4v){0.f,0.f,0.f,0.f};
  f4v S[2][2];
  S[0][0] = __builtin_amdgcn_mfma_f32_16x16x32_bf16(aq0, bk0, zero, 0,0,0);
  S[0][1] = __builtin_amdgcn_mfma_f32_16x16x32_bf16(aq0, bk1, zero, 0,0,0);
  S[1][0] = __builtin_amdgcn_mfma_f32_16x16x32_bf16(aq1, bk0, zero, 0,0,0);
  S[1][1] = __builtin_amdgcn_mfma_f32_16x16x32_bf16(aq1, bk1, zero, 0,0,0);

  float* Dn = Dbuf + (((size_t)n*HS + hh)<<10);
#pragma unroll
  for(int mt=0;mt<2;mt++)
#pragma unroll
    for(int nt=0;nt<2;nt++)
#pragma unroll
      for(int r=0;r<4;r++){
        int row = mt*16+q*4+r, col = nt*16+l16;
        if(col<=row){
          float al = alibi[(size_t)h*TT*TT + row*TT + col];
          float v = al + S[mt][nt][r]*rsK;
          unsafeAtomicAdd(&Dn[row*32+col], __expf(v));
        }
      }
}

// ---------------- Attention phase 2: chunk-parallel weights + PV ----------------
// One 64-thread block (one wave) per (node, head, chunk-of-4-edges); stride loop covers
// deg>32. Q/K fragments loaded directly from global with register bias-add; W and V go
// through double-buffered LDS with next-edge raw prefetch so edge i+1's gather overlaps
// edge i's MFMA/exp. V stage is 32 B/lane (two uint4) — columns halfv*16..+16 of row t2v.
// Masked (col>row) positions get weight 1/deg (reference's uniform softmax over -1e30
// logits). O tile atomically accumulated into pre-zeroed attn.
__global__ __launch_bounds__(64) void k_attn_pv(
    const unsigned short* __restrict__ P,
    const float* __restrict__ alibi,
    const int* __restrict__ offs, const int* __restrict__ elist,
    const int* __restrict__ senders,
    const float* __restrict__ Dbuf,
    float* __restrict__ attn, int h0){
  __shared__ unsigned short Wb[2][32*40];
  __shared__ unsigned short Vb[2][32*40];
  int lane = threadIdx.x;
  int bx = blockIdx.x;
  int n = bx>>4, hh = (bx>>3)&1, c0 = bx&7;
  int o0 = offs[n], deg = offs[n+1]-o0;
  if(c0*4 >= deg) return;
  int h = h0+hh;
  int q = lane>>4, l16 = lane&15;
  int t2v = lane>>1, halfv = lane&1;
  const float rsK = 0.17677669529663687f;
  const float invdeg = 1.0f/(float)deg;

  size_t nb = (size_t)n*TT*PS2 + hh*32 + q*8;
  float BqF0[8], BqF1[8], BkF0[8], BkF1[8];
  ld8bf(P + nb + 64  + (size_t)l16*PS2,      BqF0);
  ld8bf(P + nb + 64  + (size_t)(16+l16)*PS2, BqF1);
  ld8bf(P + nb + 192 + (size_t)l16*PS2,      BkF0);
  ld8bf(P + nb + 192 + (size_t)(16+l16)*PS2, BkF1);

  float AlR[2][2][4];
#pragma unroll
  for(int mt=0;mt<2;mt++)
#pragma unroll
    for(int nt=0;nt<2;nt++)
#pragma unroll
      for(int r=0;r<4;r++)
        AlR[mt][nt][r] = alibi[(size_t)h*TT*TT + (mt*16+q*4+r)*TT + nt*16+l16];

  const float* Dn = Dbuf + (((size_t)n*HS + hh)<<10);
  float Dinv[2][2][4];
#pragma unroll
  for(int mt=0;mt<2;mt++)
#pragma unroll
    for(int nt=0;nt<2;nt++)
#pragma unroll
      for(int r=0;r<4;r++){
        int row = mt*16+q*4+r, col = nt*16+l16;
        float d = Dn[row*32+col];
        Dinv[mt][nt][r] = (d > 0.f) ? 1.0f/d : 0.f;
      }

  f4v O[2][2];
  f4v zero = (f4v){0.f,0.f,0.f,0.f};
#pragma unroll
  for(int mt=0;mt<2;mt++)
#pragma unroll
    for(int dt=0;dt<2;dt++) O[mt][dt] = zero;

  for(int c=c0; c*4<deg; c+=8){
    int base = o0 + c*4;
    int rem = deg - c*4;
    int cnt = rem > 4 ? 4 : rem;
    int sarr[4];
#pragma unroll
    for(int i=0;i<4;i++){
      int idx = base + (i<cnt ? i : cnt-1);
      sarr[i] = senders[elist[idx]];
    }
    // prefetch edge 0 raws
    size_t sb = (size_t)sarr[0]*TT*PS2 + hh*32;
    uint4 rA0 = ld16(P + sb + (size_t)l16*PS2 + q*8);
    uint4 rA1 = ld16(P + sb + (size_t)(16+l16)*PS2 + q*8);
    uint4 rK0 = ld16(P + sb + 128 + (size_t)l16*PS2 + q*8);
    uint4 rK1 = ld16(P + sb + 128 + (size_t)(16+l16)*PS2 + q*8);
    uint4 rVa = ld16(P + sb + 256 + (size_t)t2v*PS2 + halfv*16);
    uint4 rVb = ld16(P + sb + 256 + (size_t)t2v*PS2 + halfv*16 + 8);
    for(int i=0;i<cnt;i++){
      // issue next edge's raws (redundant re-load of current on last iter; always in-bounds)
      int i2 = (i+1<cnt) ? i+1 : i;
      size_t sb2 = (size_t)sarr[i2]*TT*PS2 + hh*32;
      uint4 nA0 = ld16(P + sb2 + (size_t)l16*PS2 + q*8);
      uint4 nA1 = ld16(P + sb2 + (size_t)(16+l16)*PS2 + q*8);
      uint4 nK0 = ld16(P + sb2 + 128 + (size_t)l16*PS2 + q*8);
      uint4 nK1 = ld16(P + sb2 + 128 + (size_t)(16+l16)*PS2 + q*8);
      uint4 nVa = ld16(P + sb2 + 256 + (size_t)t2v*PS2 + halfv*16);
      uint4 nVb = ld16(P + sb2 + 256 + (size_t)t2v*PS2 + halfv*16 + 8);

      // pack current Q/K fragments with receiver bias
      s8v aq0 = addpack(rA0, BqF0), aq1 = addpack(rA1, BqF1);
      s8v bk0 = addpack(rK0, BkF0), bk1 = addpack(rK1, BkF1);
      f4v S[2][2];
      S[0][0] = __builtin_amdgcn_mfma_f32_16x16x32_bf16(aq0, bk0, zero, 0,0,0);
      S[0][1] = __builtin_amdgcn_mfma_f32_16x16x32_bf16(aq0, bk1, zero, 0,0,0);
      S[1][0] = __builtin_amdgcn_mfma_f32_16x16x32_bf16(aq1, bk0, zero, 0,0,0);
      S[1][1] = __builtin_amdgcn_mfma_f32_16x16x32_bf16(aq1, bk1, zero, 0,0,0);

      int buf = i&1;
      // stage V^T (raw ushort copy, no float round-trip): 16 ushorts = rVa..rVb
      {
        const unsigned short* va = reinterpret_cast<const unsigned short*>(&rVa);
        const unsigned short* vb = reinterpret_cast<const unsigned short*>(&rVb);
#pragma unroll
        for(int j=0;j<8;j++){
          Vb[buf][(halfv*16+j)*40 + t2v]   = va[j];
          Vb[buf][(halfv*16+8+j)*40 + t2v] = vb[j];
        }
      }
      // softmax weights -> LDS (C/D layout -> A-frag layout transpose)
#pragma unroll
      for(int mt=0;mt<2;mt++)
#pragma unroll
        for(int nt=0;nt<2;nt++)
#pragma unroll
          for(int r=0;r<4;r++){
            int row = mt*16+q*4+r, col = nt*16+l16;
            float w;
            if(col<=row){
              float v = AlR[mt][nt][r] + S[mt][nt][r]*rsK;
              w = __expf(v) * Dinv[mt][nt][r];
            } else {
              w = invdeg;     // reference quirk: uniform softmax over -1e30 logits
            }
            Wb[buf][row*40 + col] = f2bfu(w);
          }
      s8v ap0 = *reinterpret_cast<const s8v*>(&Wb[buf][(l16)*40 + q*8]);
      s8v ap1 = *reinterpret_cast<const s8v*>(&Wb[buf][(16+l16)*40 + q*8]);
      s8v bv0 = *reinterpret_cast<const s8v*>(&Vb[buf][(l16)*40 + q*8]);
      s8v bv1 = *reinterpret_cast<const s8v*>(&Vb[buf][(16+l16)*40 + q*8]);
      O[0][0] = __builtin_amdgcn_mfma_f32_16x16x32_bf16(ap0, bv0, O[0][0], 0,0,0);
      O[0][1] = __builtin_amdgcn_mfma_f32_16x16x32_bf16(ap0, bv1, O[0][1], 0,0,0);
      O[1][0] = __builtin_amdgcn_mfma_f32_16x16x32_bf16(ap1, bv0, O[1][0], 0,0,0);
      O[1][1] = __builtin_amdgcn_mfma_f32_16x16x32_bf16(ap1, bv1, O[1][1], 0,0,0);

      rA0=nA0; rA1=nA1; rK0=nK0; rK1=nK1; rVa=nVa; rVb=nVb;
    }
  }

#pragma unroll
  for(int mt=0;mt<2;mt++)
#pragma unroll
    for(int dt=0;dt<2;dt++)
#pragma unroll
      for(int r=0;r<4;r++){
        int row = mt*16+q*4+r;
        unsafeAtomicAdd(&attn[((size_t)n*TT + row)*DD + h*KK + dt*16 + l16], O[mt][dt][r]);
      }
}

// ---------------- FFN GEMM (128x128 tiles, async staging) ----------------
__global__ __launch_bounds__(256) void k_gemmL(
    const unsigned short* __restrict__ A, int lda,
    const unsigned short* __restrict__ Bt, int ldb,
    unsigned short* __restrict__ Cbf, float* __restrict__ Cacc, int ldc,
    int K, const float* __restrict__ bias, int act){
  __shared__ unsigned short Asm[128*32];
  __shared__ unsigned short Bsm[128*32];
  int tid = threadIdx.x;
  int lane = tid & 63, wid = tid >> 6;
  int wrow = (wid>>1)*64, wcol = (wid&1)*64;
  int m0 = blockIdx.x*128, n0 = blockIdx.y*128;
  f4v acc[4][4];
#pragma unroll
  for(int mi=0;mi<4;mi++)
#pragma unroll
    for(int ni=0;ni<4;ni++) acc[mi][ni] = (f4v){0.f,0.f,0.f,0.f};
  int q = lane>>4, l16 = lane&15;
  int ra0 = tid>>2, ca0 = (tid&3)*8;
  int c1 = tid+256, ra1 = c1>>2, ca1 = (c1&3)*8;
  for(int k0=0;k0<K;k0+=32){
    glds16(A + (size_t)(m0+ra0)*lda + k0 + ca0, &Asm[tid*8]);
    glds16(A + (size_t)(m0+ra1)*lda + k0 + ca1, &Asm[c1*8]);
    glds16(Bt + (size_t)(n0+ra0)*ldb + k0 + ca0, &Bsm[tid*8]);
    glds16(Bt + (size_t)(n0+ra1)*ldb + k0 + ca1, &Bsm[c1*8]);
    __syncthreads();
    s8v af[4], bfr[4];
#pragma unroll
    for(int mi=0;mi<4;mi++) af[mi]  = *reinterpret_cast<const s8v*>(&Asm[(wrow+mi*16+l16)*32 + q*8]);
#pragma unroll
    for(int ni=0;ni<4;ni++) bfr[ni] = *reinterpret_cast<const s8v*>(&Bsm[(wcol+ni*16+l16)*32 + q*8]);
#pragma unroll
    for(int mi=0;mi<4;mi++)
#pragma unroll
      for(int ni=0;ni<4;ni++)
        acc[mi][ni] = __builtin_amdgcn_mfma_f32_16x16x32_bf16(af[mi], bfr[ni], acc[mi][ni], 0, 0, 0);
    __syncthreads();
  }
#pragma unroll
  for(int mi=0;mi<4;mi++)
#pragma unroll
    for(int ni=0;ni<4;ni++){
      int ccol = n0 + wcol + ni*16 + l16;
      float bv = bias ? bias[ccol] : 0.f;
#pragma unroll
      for(int r=0;r<4;r++){
        int crow = m0 + wrow + mi*16 + q*4 + r;
        float v = acc[mi][ni][r] + bv;
        if(act==1){
          float x = v;
          float z = 0.7978845608028654f*(x + 0.044715f*x*x*x);
          float t = 1.f - 2.f/(__expf(2.f*z) + 1.f);   // tanh(z), overflow-safe
          v = 0.5f*x*(1.f + t);
        }
        if(Cacc) Cacc[(size_t)crow*ldc + ccol] += v;
        else     Cbf[(size_t)crow*ldc + ccol] = f2bfu(v);
      }
    }
}

// ---------------- Orchestration ----------------
extern "C" void kernel_launch(void* const* d_in, const int* in_sizes, int n_in,
                              void* d_out, int out_size, void* d_ws, size_t ws_size,
                              hipStream_t stream) {
  const float* nodes    = (const float*)d_in[0];
  const int*   senders  = (const int*)d_in[1];
  const int*   receivers= (const int*)d_in[2];
  const float* alibi    = (const float*)d_in[3];
  const float* lnq_s    = (const float*)d_in[4];
  const float* lnq_o    = (const float*)d_in[5];
  const float* Wq       = (const float*)d_in[6];
  const float* bq       = (const float*)d_in[7];
  const float* Wk       = (const float*)d_in[8];
  const float* bk       = (const float*)d_in[9];
  const float* Wv       = (const float*)d_in[10];
  const float* bv       = (const float*)d_in[11];
  const float* lnm_s    = (const float*)d_in[12];
  const float* lnm_o    = (const float*)d_in[13];
  const float* W1       = (const float*)d_in[14];
  const float* b1       = (const float*)d_in[15];
  const float* W2       = (const float*)d_in[16];
  const float* b2       = (const float*)d_in[17];
  const float* lno_s    = (const float*)d_in[18];
  const float* lno_o    = (const float*)d_in[19];

  char* ws = (char*)d_ws;
  // layout (~153.7 MiB; proven safe in round-2):
  size_t o_nnorm = 0;                         // bf16 ROWS*256 = 33.5 MB ; H1c overlay later
  size_t o_P2    = 33554432;                  // bf16 ROWS*320 = 41.9 MB ; Xm overlay later
  size_t o_attn  = 75497472;                  // fp32 ROWS*256 = 67.1 MB (gets D2 accumulated)
  size_t o_w1t   = 142606336;                 // 1024x256 bf16 = 524288
  size_t o_w2t   = 143130624;                 // 256x1024 bf16 = 524288
  size_t o_wall  = 143654912;                 // 4*320*256 bf16 = 655360
  size_t o_ball  = 144310272;                 // 4*320 fp32 = 5120
  size_t o_dbuf  = 144315392;                 // NN*HS*1024 fp32 = 16,777,216
  size_t o_csr   = 161092608;
  size_t o_deg   = o_csr;
  size_t o_offs  = o_csr + 8192;
  size_t o_cur   = o_csr + 16640;
  size_t o_elist = o_csr + 24832;

  unsigned short* nnorm = (unsigned short*)(ws + o_nnorm);
  unsigned short* P2    = (unsigned short*)(ws + o_P2);
  float* attn = (float*)(ws + o_attn);
  unsigned short* w1t   = (unsigned short*)(ws + o_w1t);
  unsigned short* w2t   = (unsigned short*)(ws + o_w2t);
  unsigned short* WTall = (unsigned short*)(ws + o_wall);
  float* biasall = (float*)(ws + o_ball);
  float* Dbuf    = (float*)(ws + o_dbuf);
  int* deg    = (int*)(ws + o_deg);
  int* offs   = (int*)(ws + o_offs);
  int* cursor = (int*)(ws + o_cur);
  int* elist  = (int*)(ws + o_elist);
  unsigned short* H1c = (unsigned short*)(ws + o_nnorm);  // overlay (nnorm dead after last projg)
  unsigned short* Xm  = (unsigned short*)(ws + o_P2);     // overlay (P2 dead after attention)

  // CSR build
  k_zero_i32<<<8, 256, 0, stream>>>(deg, NN);
  k_hist<<<EE/256, 256, 0, stream>>>(receivers, deg);
  k_scan<<<1, 256, 0, stream>>>(deg, offs, cursor);
  k_scatter<<<EE/256, 256, 0, stream>>>(receivers, cursor, elist);

  // LN(nodes) -> nnorm (bf16)
  k_ln_f2b<<<ROWS/4, 256, 0, stream>>>(nodes, lnq_s, lnq_o, nnorm);

  // weights: W1/W2 transposed (fp32->bf16); fused projection weights
  k_transpose<<<dim3(32,8), 256, 0, stream>>>(W1, w1t, 256, 1024);
  k_transpose<<<dim3(8,32), 256, 0, stream>>>(W2, w2t, 1024, 256);
  k_buildw<<<4*320, 256, 0, stream>>>(Wq, Wk, Wv, bq, bk, bv, WTall, biasall);

  // zero attention accumulator (k_attn_pv atomically accumulates into it)
  k_zero_f4<<<ROWS*DD/1024, 256, 0, stream>>>((float4*)attn, ROWS*DD/4);

  // attention: 4 passes of 2 heads
  for(int p=0;p<HH/HS;p++){
    k_zero_f4<<<NN*HS*1024/1024, 256, 0, stream>>>((float4*)Dbuf, NN*HS*1024/4);
    k_projg<<<dim3(ROWS/128, 5), 256, 0, stream>>>(nnorm, WTall + (size_t)p*320*256,
                                                   biasall + p*320, P2);
    k_attn_stats<<<EE*HS, 64, 0, stream>>>(P2, alibi, receivers, senders, Dbuf, p*HS);
    k_attn_pv<<<NN*HS*8, 64, 0, stream>>>(P2, alibi, offs, elist, senders, Dbuf, attn, p*HS);
  }

  // FFN: Xm = LN(attn); 4 row-chunks of 16384: H1c = gelu(Xm@W1+b1); attn += H1c@W2+b2
  k_ln_f2b<<<ROWS/4, 256, 0, stream>>>(attn, lnm_s, lnm_o, Xm);
  for(int cch=0; cch<4; cch++){
    const unsigned short* Xc = Xm + (size_t)cch*16384*256;
    k_gemmL<<<dim3(128, 8), 256, 0, stream>>>(Xc, 256, w1t, 256,
                                              H1c, nullptr, 1024, 256, b1, 1);
    k_gemmL<<<dim3(128, 2), 256, 0, stream>>>(H1c, 1024, w2t, 1024,
                                              nullptr, attn + (size_t)cch*16384*256, 256,
                                              1024, b2, 0);
  }

  // out = LN(nodes + attn)
  k_final<<<ROWS/4, 256, 0, stream>>>(nodes, attn, lno_s, lno_o, (float*)d_out);
}

// Round 6
// 1063.232 us; speedup vs baseline: 1.3072x; 1.3072x over previous
//
#include <hip/hip_runtime.h>
#include <hip/hip_bf16.h>
#include <math.h>

#define NN 2048
#define TT 32
#define DD 256
#define HH 8
#define KK 32
#define EE 8192
#define ROWS (NN*TT)    // 65536
#define HS 2            // heads per pass
#define PS2 320         // P row stride: [Aq|Bq|Ak|Bk|V] x (HS*32) cols

typedef short s8v __attribute__((ext_vector_type(8)));
typedef float f4v __attribute__((ext_vector_type(4)));

typedef __attribute__((address_space(3))) unsigned char lds_t;
typedef __attribute__((address_space(1))) const unsigned char glob_t;
__device__ __forceinline__ void glds16(const void* g, void* l){
  __builtin_amdgcn_global_load_lds((glob_t*)g, (lds_t*)l, 16, 0, 0);
}

__device__ __forceinline__ float bfu2f(unsigned short u){
  return __uint_as_float(((unsigned int)u)<<16);
}
__device__ __forceinline__ unsigned short f2bfu(float f){
  __hip_bfloat16 h = __float2bfloat16(f);
  return *reinterpret_cast<unsigned short*>(&h);
}
__device__ __forceinline__ void ld8bf(const unsigned short* p, float* o){
  uint4 u = *reinterpret_cast<const uint4*>(p);
  const unsigned short* us = reinterpret_cast<const unsigned short*>(&u);
#pragma unroll
  for(int i=0;i<8;i++) o[i] = bfu2f(us[i]);
}
__device__ __forceinline__ uint4 ld16(const unsigned short* p){
  return *reinterpret_cast<const uint4*>(p);
}
// raw bf16x8 + fp32 bias fragment -> bf16 fragment
__device__ __forceinline__ s8v addpack(uint4 raw, const float* B){
  const unsigned short* us = reinterpret_cast<const unsigned short*>(&raw);
  s8v r;
#pragma unroll
  for(int j=0;j<8;j++) r[j] = (short)f2bfu(bfu2f(us[j]) + B[j]);
  return r;
}

// ---------------- CSR build ----------------
__global__ void k_zero_i32(int* p, int n){
  int i = blockIdx.x*256 + threadIdx.x;
  if(i<n) p[i]=0;
}
__global__ void k_zero_f4(float4* p, int n4){
  int i = blockIdx.x*256 + threadIdx.x;
  if(i<n4) p[i] = make_float4(0.f,0.f,0.f,0.f);
}
__global__ void k_hist(const int* __restrict__ recv, int* __restrict__ deg){
  int e = blockIdx.x*256 + threadIdx.x;
  if(e<EE) atomicAdd(&deg[recv[e]], 1);
}
__global__ void k_scan(const int* __restrict__ deg, int* __restrict__ offs, int* __restrict__ cursor){
  __shared__ int buf[2][NN];
  int tid = threadIdx.x;
  for(int i=tid;i<NN;i+=256) buf[0][i] = deg[i];
  __syncthreads();
  int src = 0;
  for(int off=1; off<NN; off<<=1){
    for(int i=tid;i<NN;i+=256){
      int v = buf[src][i];
      if(i>=off) v += buf[src][i-off];
      buf[1-src][i] = v;
    }
    src = 1-src;
    __syncthreads();
  }
  for(int i=tid;i<NN;i+=256){
    int ex = (i==0)?0:buf[src][i-1];
    offs[i]=ex; cursor[i]=ex;
  }
  if(tid==0) offs[NN]=EE;
}
__global__ void k_scatter(const int* __restrict__ recv, int* __restrict__ cursor, int* __restrict__ elist){
  int e = blockIdx.x*256 + threadIdx.x;
  if(e<EE){
    int pos = atomicAdd(&cursor[recv[e]], 1);
    elist[pos] = e;
  }
}

// ---------------- LayerNorm: fp32 in -> bf16 out ----------------
__global__ __launch_bounds__(256) void k_ln_f2b(const float* __restrict__ x,
    const float* __restrict__ sc, const float* __restrict__ of,
    unsigned short* __restrict__ out){
  int gw = (blockIdx.x*256 + threadIdx.x)>>6;
  int lane = threadIdx.x & 63;
  size_t base = (size_t)gw*DD + lane*4;
  float4 xv = *reinterpret_cast<const float4*>(x + base);
  float v[4] = {xv.x, xv.y, xv.z, xv.w};
  float s = v[0]+v[1]+v[2]+v[3];
  float q = v[0]*v[0]+v[1]*v[1]+v[2]*v[2]+v[3]*v[3];
#pragma unroll
  for(int o=32;o>0;o>>=1){ s += __shfl_xor(s,o); q += __shfl_xor(q,o); }
  float mean = s*(1.0f/DD);
  float var = q*(1.0f/DD) - mean*mean;
  float rs = rsqrtf(var + 1e-5f);
  float4 scv = *reinterpret_cast<const float4*>(sc + lane*4);
  float4 ofv = *reinterpret_cast<const float4*>(of + lane*4);
  ushort4 o4;
  o4.x = f2bfu((v[0]-mean)*rs*scv.x+ofv.x);
  o4.y = f2bfu((v[1]-mean)*rs*scv.y+ofv.y);
  o4.z = f2bfu((v[2]-mean)*rs*scv.z+ofv.z);
  o4.w = f2bfu((v[3]-mean)*rs*scv.w+ofv.w);
  *reinterpret_cast<ushort4*>(out + base) = o4;
}

// out = LN(nodes + attn_total), fp32 out   (attn buffer already includes D2)
__global__ __launch_bounds__(256) void k_final(
    const float* __restrict__ nodes, const float* __restrict__ attn,
    const float* __restrict__ sc, const float* __restrict__ of,
    float* __restrict__ out){
  int gw = (blockIdx.x*256 + threadIdx.x)>>6;
  int lane = threadIdx.x & 63;
  size_t base = (size_t)gw*DD + lane*4;
  float4 a4 = *reinterpret_cast<const float4*>(nodes + base);
  float4 c4 = *reinterpret_cast<const float4*>(attn + base);
  float v[4];
  v[0]=a4.x+c4.x; v[1]=a4.y+c4.y; v[2]=a4.z+c4.z; v[3]=a4.w+c4.w;
  float s = v[0]+v[1]+v[2]+v[3];
  float q = v[0]*v[0]+v[1]*v[1]+v[2]*v[2]+v[3]*v[3];
#pragma unroll
  for(int o=32;o>0;o>>=1){ s += __shfl_xor(s,o); q += __shfl_xor(q,o); }
  float mean = s*(1.0f/DD);
  float var = q*(1.0f/DD) - mean*mean;
  float rs = rsqrtf(var + 1e-5f);
  float4 scv = *reinterpret_cast<const float4*>(sc + lane*4);
  float4 ofv = *reinterpret_cast<const float4*>(of + lane*4);
  float4 o4;
  o4.x = (v[0]-mean)*rs*scv.x+ofv.x;
  o4.y = (v[1]-mean)*rs*scv.y+ofv.y;
  o4.z = (v[2]-mean)*rs*scv.z+ofv.z;
  o4.w = (v[3]-mean)*rs*scv.w+ofv.w;
  *reinterpret_cast<float4*>(out + base) = o4;
}

// ---------------- Weight transpose + fp32->bf16: in[R][C] f32 -> out[C][R] bf16 ----------------
__global__ void k_transpose(const float* __restrict__ in, unsigned short* __restrict__ out,
                            int R, int C){
  __shared__ unsigned short tile[32][33];
  int c0 = blockIdx.x*32, r0 = blockIdx.y*32;
  int tx = threadIdx.x & 31, ty = threadIdx.x >> 5;
  for(int i=ty;i<32;i+=8){
    int r = r0+i, c = c0+tx;
    tile[i][tx] = (r<R && c<C) ? f2bfu(in[(size_t)r*C + c]) : (unsigned short)0;
  }
  __syncthreads();
  for(int i=ty;i<32;i+=8){
    int c = c0+i, r = r0+tx;
    if(c<C && r<R) out[(size_t)c*R + r] = tile[tx][i];
  }
}

// ---------------- Build fused per-pass projection weights ----------------
__global__ void k_buildw(const float* __restrict__ Wq, const float* __restrict__ Wk,
                         const float* __restrict__ Wv,
                         const float* __restrict__ bq, const float* __restrict__ bk,
                         const float* __restrict__ bv,
                         unsigned short* __restrict__ WTall, float* __restrict__ biasall){
  int bx = blockIdx.x;            // p*320 + c
  int p = bx/320, c = bx - p*320;
  int k = threadIdx.x;
  int g = c>>6, hh = (c>>5)&1, j = c&31;
  int h = p*HS + hh;
  int col = h*32 + j;
  float w;
  if(g==0)      w = Wq[(size_t)k*256 + col];
  else if(g==1) w = Wq[(size_t)(256+k)*256 + col];
  else if(g==2) w = Wk[(size_t)k*256 + col];
  else if(g==3) w = Wk[(size_t)(256+k)*256 + col];
  else          w = Wv[(size_t)k*256 + col];
  WTall[((size_t)bx)*256 + k] = f2bfu(w);
  if(k==0){
    float b = 0.f;
    if(g==0) b = bq[col];
    else if(g==2) b = bk[col];
    else if(g==4) b = bv[col];
    biasall[bx] = b;
  }
}

// ---------------- Projection GEMM: P2[ROWS][320] = nnorm @ WTall_p^T + bias ----------------
__global__ __launch_bounds__(256) void k_projg(
    const unsigned short* __restrict__ A,      // [ROWS][256]
    const unsigned short* __restrict__ Bt,     // [320][256] for this pass
    const float* __restrict__ bias,            // [320]
    unsigned short* __restrict__ P){
  __shared__ unsigned short Asm[128*32];
  __shared__ unsigned short Bsm[64*32];
  int tid = threadIdx.x, lane = tid&63;
  int wid = tid>>6;
  int wrow = (wid>>1)*64, wcol = (wid&1)*32;
  int m0 = blockIdx.x*128, n0 = blockIdx.y*64;
  f4v acc[4][2];
#pragma unroll
  for(int mi=0;mi<4;mi++)
#pragma unroll
    for(int ni=0;ni<2;ni++) acc[mi][ni] = (f4v){0.f,0.f,0.f,0.f};
  int q = lane>>4, l16 = lane&15;
  int ra0 = tid>>2, ca0 = (tid&3)*8;
  int c1 = tid+256, ra1 = c1>>2, ca1 = (c1&3)*8;
  for(int k0=0;k0<256;k0+=32){
    glds16(A + (size_t)(m0+ra0)*256 + k0 + ca0, &Asm[tid*8]);
    glds16(A + (size_t)(m0+ra1)*256 + k0 + ca1, &Asm[c1*8]);
    glds16(Bt + (size_t)(n0+ra0)*256 + k0 + ca0, &Bsm[tid*8]);
    __syncthreads();
    s8v af[4], bfr[2];
#pragma unroll
    for(int mi=0;mi<4;mi++) af[mi]  = *reinterpret_cast<const s8v*>(&Asm[(wrow+mi*16+l16)*32 + q*8]);
#pragma unroll
    for(int ni=0;ni<2;ni++) bfr[ni] = *reinterpret_cast<const s8v*>(&Bsm[(wcol+ni*16+l16)*32 + q*8]);
#pragma unroll
    for(int mi=0;mi<4;mi++)
#pragma unroll
      for(int ni=0;ni<2;ni++)
        acc[mi][ni] = __builtin_amdgcn_mfma_f32_16x16x32_bf16(af[mi], bfr[ni], acc[mi][ni], 0, 0, 0);
    __syncthreads();
  }
#pragma unroll
  for(int mi=0;mi<4;mi++)
#pragma unroll
    for(int ni=0;ni<2;ni++){
      int ccol = n0 + wcol + ni*16 + l16;
      float bvv = bias[ccol];
#pragma unroll
      for(int r=0;r<4;r++){
        int crow = m0 + wrow + mi*16 + q*4 + r;
        P[(size_t)crow*PS2 + ccol] = f2bfu(acc[mi][ni][r] + bvv);
      }
    }
}

// ---------------- Attention phase 1: edge-parallel denominator accumulation ----------------
// One 64-thread block (one wave) per (edge, head). LDS-free: Q/K MFMA fragments are loaded
// directly from P rows (fragment layout row=l16, k=q*8+j is a contiguous 16B slice), receiver
// bias fragments hoisted and added in registers. D[n][hh][row][col] += exp(logit) over causal
// positions; masked positions form their own uniform softmax handled in k_attn_pv.
__global__ __launch_bounds__(64) void k_attn_stats(
    const unsigned short* __restrict__ P,
    const float* __restrict__ alibi,
    const int* __restrict__ receivers, const int* __restrict__ senders,
    float* __restrict__ Dbuf, int h0){
  int lane = threadIdx.x;
  int g = blockIdx.x;               // [0, EE*HS)
  int e = g>>1, hh = g&1, h = h0+hh;
  int q = lane>>4, l16 = lane&15;
  const float rsK = 0.17677669529663687f;   // 1/sqrt(32)

  int n = receivers[e], s = senders[e];
  size_t nb = (size_t)n*TT*PS2 + hh*32 + q*8;
  size_t sb = (size_t)s*TT*PS2 + hh*32 + q*8;

  // sender fragments (raw) — issue early
  uint4 rA0 = ld16(P + sb + (size_t)l16*PS2);
  uint4 rA1 = ld16(P + sb + (size_t)(16+l16)*PS2);
  uint4 rK0 = ld16(P + sb + 128 + (size_t)l16*PS2);
  uint4 rK1 = ld16(P + sb + 128 + (size_t)(16+l16)*PS2);
  // receiver bias fragments
  float BqF0[8], BqF1[8], BkF0[8], BkF1[8];
  ld8bf(P + nb + 64  + (size_t)l16*PS2,      BqF0);
  ld8bf(P + nb + 64  + (size_t)(16+l16)*PS2, BqF1);
  ld8bf(P + nb + 192 + (size_t)l16*PS2,      BkF0);
  ld8bf(P + nb + 192 + (size_t)(16+l16)*PS2, BkF1);

  s8v aq0 = addpack(rA0, BqF0), aq1 = addpack(rA1, BqF1);
  s8v bk0 = addpack(rK0, BkF0), bk1 = addpack(rK1, BkF1);
  f4v zero = (f4v){0.f,0.f,0.f,0.f};
  f4v S[2][2];
  S[0][0] = __builtin_amdgcn_mfma_f32_16x16x32_bf16(aq0, bk0, zero, 0,0,0);
  S[0][1] = __builtin_amdgcn_mfma_f32_16x16x32_bf16(aq0, bk1, zero, 0,0,0);
  S[1][0] = __builtin_amdgcn_mfma_f32_16x16x32_bf16(aq1, bk0, zero, 0,0,0);
  S[1][1] = __builtin_amdgcn_mfma_f32_16x16x32_bf16(aq1, bk1, zero, 0,0,0);

  float* Dn = Dbuf + (((size_t)n*HS + hh)<<10);
#pragma unroll
  for(int mt=0;mt<2;mt++)
#pragma unroll
    for(int nt=0;nt<2;nt++)
#pragma unroll
      for(int r=0;r<4;r++){
        int row = mt*16+q*4+r, col = nt*16+l16;
        if(col<=row){
          float al = alibi[(size_t)h*TT*TT + row*TT + col];
          float v = al + S[mt][nt][r]*rsK;
          unsafeAtomicAdd(&Dn[row*32+col], __expf(v));
        }
      }
}

// ---------------- Attention phase 2: chunk-parallel weights + PV ----------------
// One 64-thread block (one wave) per (node, head, chunk-of-4-edges); stride loop covers
// deg>32. Block-index layout puts the NODE in the LOW bits (bx & 2047) and the chunk slot
// in the HIGH bits: MI355X round-robins blockIdx across the 8 XCDs by low bits, and with
// mean degree ~4 only chunk 0 does work — chunk-in-low-bits piled every working block onto
// XCD 0 (round-4 counters: concurrency ~330 = one XCD). Node-in-low-bits spreads working
// blocks across all 8 XCDs. Q/K fragments loaded directly from global with register
// bias-add; W and V go through double-buffered LDS with next-edge raw prefetch. Masked
// (col>row) positions get weight 1/deg (reference's uniform softmax over -1e30 logits).
// O tile atomically accumulated into pre-zeroed attn.
__global__ __launch_bounds__(64) void k_attn_pv(
    const unsigned short* __restrict__ P,
    const float* __restrict__ alibi,
    const int* __restrict__ offs, const int* __restrict__ elist,
    const int* __restrict__ senders,
    const float* __restrict__ Dbuf,
    float* __restrict__ attn, int h0){
  __shared__ unsigned short Wb[2][32*40];
  __shared__ unsigned short Vb[2][32*40];
  int lane = threadIdx.x;
  int bx = blockIdx.x;
  int n = bx & (NN-1);              // node in LOW bits -> uniform XCD spread
  int rest = bx >> 11;              // NN = 2048 = 1<<11
  int hh = rest & 1, c0 = rest >> 1;
  int o0 = offs[n], deg = offs[n+1]-o0;
  if(c0*4 >= deg) return;
  int h = h0+hh;
  int q = lane>>4, l16 = lane&15;
  int t2v = lane>>1, halfv = lane&1;
  const float rsK = 0.17677669529663687f;
  const float invdeg = 1.0f/(float)deg;

  size_t nb = (size_t)n*TT*PS2 + hh*32 + q*8;
  float BqF0[8], BqF1[8], BkF0[8], BkF1[8];
  ld8bf(P + nb + 64  + (size_t)l16*PS2,      BqF0);
  ld8bf(P + nb + 64  + (size_t)(16+l16)*PS2, BqF1);
  ld8bf(P + nb + 192 + (size_t)l16*PS2,      BkF0);
  ld8bf(P + nb + 192 + (size_t)(16+l16)*PS2, BkF1);

  float AlR[2][2][4];
#pragma unroll
  for(int mt=0;mt<2;mt++)
#pragma unroll
    for(int nt=0;nt<2;nt++)
#pragma unroll
      for(int r=0;r<4;r++)
        AlR[mt][nt][r] = alibi[(size_t)h*TT*TT + (mt*16+q*4+r)*TT + nt*16+l16];

  const float* Dn = Dbuf + (((size_t)n*HS + hh)<<10);
  float Dinv[2][2][4];
#pragma unroll
  for(int mt=0;mt<2;mt++)
#pragma unroll
    for(int nt=0;nt<2;nt++)
#pragma unroll
      for(int r=0;r<4;r++){
        int row = mt*16+q*4+r, col = nt*16+l16;
        float d = Dn[row*32+col];
        Dinv[mt][nt][r] = (d > 0.f) ? 1.0f/d : 0.f;
      }

  f4v O[2][2];
  f4v zero = (f4v){0.f,0.f,0.f,0.f};
#pragma unroll
  for(int mt=0;mt<2;mt++)
#pragma unroll
    for(int dt=0;dt<2;dt++) O[mt][dt] = zero;

  for(int c=c0; c*4<deg; c+=8){
    int base = o0 + c*4;
    int rem = deg - c*4;
    int cnt = rem > 4 ? 4 : rem;
    int sarr[4];
#pragma unroll
    for(int i=0;i<4;i++){
      int idx = base + (i<cnt ? i : cnt-1);
      sarr[i] = senders[elist[idx]];
    }
    // prefetch edge 0 raws
    size_t sb = (size_t)sarr[0]*TT*PS2 + hh*32;
    uint4 rA0 = ld16(P + sb + (size_t)l16*PS2 + q*8);
    uint4 rA1 = ld16(P + sb + (size_t)(16+l16)*PS2 + q*8);
    uint4 rK0 = ld16(P + sb + 128 + (size_t)l16*PS2 + q*8);
    uint4 rK1 = ld16(P + sb + 128 + (size_t)(16+l16)*PS2 + q*8);
    uint4 rVa = ld16(P + sb + 256 + (size_t)t2v*PS2 + halfv*16);
    uint4 rVb = ld16(P + sb + 256 + (size_t)t2v*PS2 + halfv*16 + 8);
    for(int i=0;i<cnt;i++){
      // issue next edge's raws (redundant re-load of current on last iter; always in-bounds)
      int i2 = (i+1<cnt) ? i+1 : i;
      size_t sb2 = (size_t)sarr[i2]*TT*PS2 + hh*32;
      uint4 nA0 = ld16(P + sb2 + (size_t)l16*PS2 + q*8);
      uint4 nA1 = ld16(P + sb2 + (size_t)(16+l16)*PS2 + q*8);
      uint4 nK0 = ld16(P + sb2 + 128 + (size_t)l16*PS2 + q*8);
      uint4 nK1 = ld16(P + sb2 + 128 + (size_t)(16+l16)*PS2 + q*8);
      uint4 nVa = ld16(P + sb2 + 256 + (size_t)t2v*PS2 + halfv*16);
      uint4 nVb = ld16(P + sb2 + 256 + (size_t)t2v*PS2 + halfv*16 + 8);

      // pack current Q/K fragments with receiver bias
      s8v aq0 = addpack(rA0, BqF0), aq1 = addpack(rA1, BqF1);
      s8v bk0 = addpack(rK0, BkF0), bk1 = addpack(rK1, BkF1);
      f4v S[2][2];
      S[0][0] = __builtin_amdgcn_mfma_f32_16x16x32_bf16(aq0, bk0, zero, 0,0,0);
      S[0][1] = __builtin_amdgcn_mfma_f32_16x16x32_bf16(aq0, bk1, zero, 0,0,0);
      S[1][0] = __builtin_amdgcn_mfma_f32_16x16x32_bf16(aq1, bk0, zero, 0,0,0);
      S[1][1] = __builtin_amdgcn_mfma_f32_16x16x32_bf16(aq1, bk1, zero, 0,0,0);

      int buf = i&1;
      // stage V^T (raw ushort copy, no float round-trip): 16 ushorts = rVa..rVb
      {
        const unsigned short* va = reinterpret_cast<const unsigned short*>(&rVa);
        const unsigned short* vb = reinterpret_cast<const unsigned short*>(&rVb);
#pragma unroll
        for(int j=0;j<8;j++){
          Vb[buf][(halfv*16+j)*40 + t2v]   = va[j];
          Vb[buf][(halfv*16+8+j)*40 + t2v] = vb[j];
        }
      }
      // softmax weights -> LDS (C/D layout -> A-frag layout transpose)
#pragma unroll
      for(int mt=0;mt<2;mt++)
#pragma unroll
        for(int nt=0;nt<2;nt++)
#pragma unroll
          for(int r=0;r<4;r++){
            int row = mt*16+q*4+r, col = nt*16+l16;
            float w;
            if(col<=row){
              float v = AlR[mt][nt][r] + S[mt][nt][r]*rsK;
              w = __expf(v) * Dinv[mt][nt][r];
            } else {
              w = invdeg;     // reference quirk: uniform softmax over -1e30 logits
            }
            Wb[buf][row*40 + col] = f2bfu(w);
          }
      s8v ap0 = *reinterpret_cast<const s8v*>(&Wb[buf][(l16)*40 + q*8]);
      s8v ap1 = *reinterpret_cast<const s8v*>(&Wb[buf][(16+l16)*40 + q*8]);
      s8v bv0 = *reinterpret_cast<const s8v*>(&Vb[buf][(l16)*40 + q*8]);
      s8v bv1 = *reinterpret_cast<const s8v*>(&Vb[buf][(16+l16)*40 + q*8]);
      O[0][0] = __builtin_amdgcn_mfma_f32_16x16x32_bf16(ap0, bv0, O[0][0], 0,0,0);
      O[0][1] = __builtin_amdgcn_mfma_f32_16x16x32_bf16(ap0, bv1, O[0][1], 0,0,0);
      O[1][0] = __builtin_amdgcn_mfma_f32_16x16x32_bf16(ap1, bv0, O[1][0], 0,0,0);
      O[1][1] = __builtin_amdgcn_mfma_f32_16x16x32_bf16(ap1, bv1, O[1][1], 0,0,0);

      rA0=nA0; rA1=nA1; rK0=nK0; rK1=nK1; rVa=nVa; rVb=nVb;
    }
  }

#pragma unroll
  for(int mt=0;mt<2;mt++)
#pragma unroll
    for(int dt=0;dt<2;dt++)
#pragma unroll
      for(int r=0;r<4;r++){
        int row = mt*16+q*4+r;
        unsafeAtomicAdd(&attn[((size_t)n*TT + row)*DD + h*KK + dt*16 + l16], O[mt][dt][r]);
      }
}

// ---------------- FFN GEMM (128x128 tiles, async staging) ----------------
__global__ __launch_bounds__(256) void k_gemmL(
    const unsigned short* __restrict__ A, int lda,
    const unsigned short* __restrict__ Bt, int ldb,
    unsigned short* __restrict__ Cbf, float* __restrict__ Cacc, int ldc,
    int K, const float* __restrict__ bias, int act){
  __shared__ unsigned short Asm[128*32];
  __shared__ unsigned short Bsm[128*32];
  int tid = threadIdx.x;
  int lane = tid & 63, wid = tid >> 6;
  int wrow = (wid>>1)*64, wcol = (wid&1)*64;
  int m0 = blockIdx.x*128, n0 = blockIdx.y*128;
  f4v acc[4][4];
#pragma unroll
  for(int mi=0;mi<4;mi++)
#pragma unroll
    for(int ni=0;ni<4;ni++) acc[mi][ni] = (f4v){0.f,0.f,0.f,0.f};
  int q = lane>>4, l16 = lane&15;
  int ra0 = tid>>2, ca0 = (tid&3)*8;
  int c1 = tid+256, ra1 = c1>>2, ca1 = (c1&3)*8;
  for(int k0=0;k0<K;k0+=32){
    glds16(A + (size_t)(m0+ra0)*lda + k0 + ca0, &Asm[tid*8]);
    glds16(A + (size_t)(m0+ra1)*lda + k0 + ca1, &Asm[c1*8]);
    glds16(Bt + (size_t)(n0+ra0)*ldb + k0 + ca0, &Bsm[tid*8]);
    glds16(Bt + (size_t)(n0+ra1)*ldb + k0 + ca1, &Bsm[c1*8]);
    __syncthreads();
    s8v af[4], bfr[4];
#pragma unroll
    for(int mi=0;mi<4;mi++) af[mi]  = *reinterpret_cast<const s8v*>(&Asm[(wrow+mi*16+l16)*32 + q*8]);
#pragma unroll
    for(int ni=0;ni<4;ni++) bfr[ni] = *reinterpret_cast<const s8v*>(&Bsm[(wcol+ni*16+l16)*32 + q*8]);
#pragma unroll
    for(int mi=0;mi<4;mi++)
#pragma unroll
      for(int ni=0;ni<4;ni++)
        acc[mi][ni] = __builtin_amdgcn_mfma_f32_16x16x32_bf16(af[mi], bfr[ni], acc[mi][ni], 0, 0, 0);
    __syncthreads();
  }
#pragma unroll
  for(int mi=0;mi<4;mi++)
#pragma unroll
    for(int ni=0;ni<4;ni++){
      int ccol = n0 + wcol + ni*16 + l16;
      float bv = bias ? bias[ccol] : 0.f;
#pragma unroll
      for(int r=0;r<4;r++){
        int crow = m0 + wrow + mi*16 + q*4 + r;
        float v = acc[mi][ni][r] + bv;
        if(act==1){
          float x = v;
          float z = 0.7978845608028654f*(x + 0.044715f*x*x*x);
          float t = 1.f - 2.f/(__expf(2.f*z) + 1.f);   // tanh(z), overflow-safe
          v = 0.5f*x*(1.f + t);
        }
        if(Cacc) Cacc[(size_t)crow*ldc + ccol] += v;
        else     Cbf[(size_t)crow*ldc + ccol] = f2bfu(v);
      }
    }
}

// ---------------- Orchestration ----------------
extern "C" void kernel_launch(void* const* d_in, const int* in_sizes, int n_in,
                              void* d_out, int out_size, void* d_ws, size_t ws_size,
                              hipStream_t stream) {
  const float* nodes    = (const float*)d_in[0];
  const int*   senders  = (const int*)d_in[1];
  const int*   receivers= (const int*)d_in[2];
  const float* alibi    = (const float*)d_in[3];
  const float* lnq_s    = (const float*)d_in[4];
  const float* lnq_o    = (const float*)d_in[5];
  const float* Wq       = (const float*)d_in[6];
  const float* bq       = (const float*)d_in[7];
  const float* Wk       = (const float*)d_in[8];
  const float* bk       = (const float*)d_in[9];
  const float* Wv       = (const float*)d_in[10];
  const float* bv       = (const float*)d_in[11];
  const float* lnm_s    = (const float*)d_in[12];
  const float* lnm_o    = (const float*)d_in[13];
  const float* W1       = (const float*)d_in[14];
  const float* b1       = (const float*)d_in[15];
  const float* W2       = (const float*)d_in[16];
  const float* b2       = (const float*)d_in[17];
  const float* lno_s    = (const float*)d_in[18];
  const float* lno_o    = (const float*)d_in[19];

  char* ws = (char*)d_ws;
  // layout (~153.7 MiB; proven safe in round-2):
  size_t o_nnorm = 0;                         // bf16 ROWS*256 = 33.5 MB ; H1c overlay later
  size_t o_P2    = 33554432;                  // bf16 ROWS*320 = 41.9 MB ; Xm overlay later
  size_t o_attn  = 75497472;                  // fp32 ROWS*256 = 67.1 MB (gets D2 accumulated)
  size_t o_w1t   = 142606336;                 // 1024x256 bf16 = 524288
  size_t o_w2t   = 143130624;                 // 256x1024 bf16 = 524288
  size_t o_wall  = 143654912;                 // 4*320*256 bf16 = 655360
  size_t o_ball  = 144310272;                 // 4*320 fp32 = 5120
  size_t o_dbuf  = 144315392;                 // NN*HS*1024 fp32 = 16,777,216
  size_t o_csr   = 161092608;
  size_t o_deg   = o_csr;
  size_t o_offs  = o_csr + 8192;
  size_t o_cur   = o_csr + 16640;
  size_t o_elist = o_csr + 24832;

  unsigned short* nnorm = (unsigned short*)(ws + o_nnorm);
  unsigned short* P2    = (unsigned short*)(ws + o_P2);
  float* attn = (float*)(ws + o_attn);
  unsigned short* w1t   = (unsigned short*)(ws + o_w1t);
  unsigned short* w2t   = (unsigned short*)(ws + o_w2t);
  unsigned short* WTall = (unsigned short*)(ws + o_wall);
  float* biasall = (float*)(ws + o_ball);
  float* Dbuf    = (float*)(ws + o_dbuf);
  int* deg    = (int*)(ws + o_deg);
  int* offs   = (int*)(ws + o_offs);
  int* cursor = (int*)(ws + o_cur);
  int* elist  = (int*)(ws + o_elist);
  unsigned short* H1c = (unsigned short*)(ws + o_nnorm);  // overlay (nnorm dead after last projg)
  unsigned short* Xm  = (unsigned short*)(ws + o_P2);     // overlay (P2 dead after attention)

  // CSR build
  k_zero_i32<<<8, 256, 0, stream>>>(deg, NN);
  k_hist<<<EE/256, 256, 0, stream>>>(receivers, deg);
  k_scan<<<1, 256, 0, stream>>>(deg, offs, cursor);
  k_scatter<<<EE/256, 256, 0, stream>>>(receivers, cursor, elist);

  // LN(nodes) -> nnorm (bf16)
  k_ln_f2b<<<ROWS/4, 256, 0, stream>>>(nodes, lnq_s, lnq_o, nnorm);

  // weights: W1/W2 transposed (fp32->bf16); fused projection weights
  k_transpose<<<dim3(32,8), 256, 0, stream>>>(W1, w1t, 256, 1024);
  k_transpose<<<dim3(8,32), 256, 0, stream>>>(W2, w2t, 1024, 256);
  k_buildw<<<4*320, 256, 0, stream>>>(Wq, Wk, Wv, bq, bk, bv, WTall, biasall);

  // zero attention accumulator (k_attn_pv atomically accumulates into it)
  k_zero_f4<<<ROWS*DD/1024, 256, 0, stream>>>((float4*)attn, ROWS*DD/4);

  // attention: 4 passes of 2 heads
  for(int p=0;p<HH/HS;p++){
    k_zero_f4<<<NN*HS*1024/1024, 256, 0, stream>>>((float4*)Dbuf, NN*HS*1024/4);
    k_projg<<<dim3(ROWS/128, 5), 256, 0, stream>>>(nnorm, WTall + (size_t)p*320*256,
                                                   biasall + p*320, P2);
    k_attn_stats<<<EE*HS, 64, 0, stream>>>(P2, alibi, receivers, senders, Dbuf, p*HS);
    k_attn_pv<<<NN*HS*8, 64, 0, stream>>>(P2, alibi, offs, elist, senders, Dbuf, attn, p*HS);
  }

  // FFN: Xm = LN(attn); 4 row-chunks of 16384: H1c = gelu(Xm@W1+b1); attn += H1c@W2+b2
  k_ln_f2b<<<ROWS/4, 256, 0, stream>>>(attn, lnm_s, lnm_o, Xm);
  for(int cch=0; cch<4; cch++){
    const unsigned short* Xc = Xm + (size_t)cch*16384*256;
    k_gemmL<<<dim3(128, 8), 256, 0, stream>>>(Xc, 256, w1t, 256,
                                              H1c, nullptr, 1024, 256, b1, 1);
    k_gemmL<<<dim3(128, 2), 256, 0, stream>>>(H1c, 1024, w2t, 1024,
                                              nullptr, attn + (size_t)cch*16384*256, 256,
                                              1024, b2, 0);
  }

  // out = LN(nodes + attn)
  k_final<<<ROWS/4, 256, 0, stream>>>(nodes, attn, lno_s, lno_o, (float*)d_out);
}

// Round 9
// 1016.576 us; speedup vs baseline: 1.3672x; 1.0459x over previous
//
#include <hip/hip_runtime.h>
#include <hip/hip_bf16.h>
#include <math.h>

#define NN 2048
#define TT 32
#define DD 256
#define HH 8
#define KK 32
#define EE 8192
#define ROWS (NN*TT)    // 65536
#define PS 160          // P row stride: [Aq|Bq|Ak|Bk|V] x 32 cols (1 head per pass)

typedef short s8v __attribute__((ext_vector_type(8)));
typedef float f4v __attribute__((ext_vector_type(4)));

typedef __attribute__((address_space(3))) unsigned char lds_t;
typedef __attribute__((address_space(1))) const unsigned char glob_t;
__device__ __forceinline__ void glds16(const void* g, void* l){
  __builtin_amdgcn_global_load_lds((glob_t*)g, (lds_t*)l, 16, 0, 0);
}

__device__ __forceinline__ float bfu2f(unsigned short u){
  return __uint_as_float(((unsigned int)u)<<16);
}
__device__ __forceinline__ unsigned short f2bfu(float f){
  __hip_bfloat16 h = __float2bfloat16(f);
  return *reinterpret_cast<unsigned short*>(&h);
}
__device__ __forceinline__ void ld8bf(const unsigned short* p, float* o){
  uint4 u = *reinterpret_cast<const uint4*>(p);
  const unsigned short* us = reinterpret_cast<const unsigned short*>(&u);
#pragma unroll
  for(int i=0;i<8;i++) o[i] = bfu2f(us[i]);
}
__device__ __forceinline__ uint4 ld16(const unsigned short* p){
  return *reinterpret_cast<const uint4*>(p);
}
// raw bf16x8 + fp32 bias fragment -> bf16 fragment
__device__ __forceinline__ s8v addpack(uint4 raw, const float* B){
  const unsigned short* us = reinterpret_cast<const unsigned short*>(&raw);
  s8v r;
#pragma unroll
  for(int j=0;j<8;j++) r[j] = (short)f2bfu(bfu2f(us[j]) + B[j]);
  return r;
}

// ---------------- CSR build ----------------
__global__ void k_zero_i32(int* p, int n){
  int i = blockIdx.x*256 + threadIdx.x;
  if(i<n) p[i]=0;
}
__global__ void k_zero_f4(float4* p, int n4){
  int i = blockIdx.x*256 + threadIdx.x;
  if(i<n4) p[i] = make_float4(0.f,0.f,0.f,0.f);
}
__global__ void k_hist(const int* __restrict__ recv, int* __restrict__ deg){
  int e = blockIdx.x*256 + threadIdx.x;
  if(e<EE) atomicAdd(&deg[recv[e]], 1);
}
__global__ void k_scan(const int* __restrict__ deg, int* __restrict__ offs, int* __restrict__ cursor){
  __shared__ int buf[2][NN];
  int tid = threadIdx.x;
  for(int i=tid;i<NN;i+=256) buf[0][i] = deg[i];
  __syncthreads();
  int src = 0;
  for(int off=1; off<NN; off<<=1){
    for(int i=tid;i<NN;i+=256){
      int v = buf[src][i];
      if(i>=off) v += buf[src][i-off];
      buf[1-src][i] = v;
    }
    src = 1-src;
    __syncthreads();
  }
  for(int i=tid;i<NN;i+=256){
    int ex = (i==0)?0:buf[src][i-1];
    offs[i]=ex; cursor[i]=ex;
  }
  if(tid==0) offs[NN]=EE;
}
__global__ void k_scatter(const int* __restrict__ recv, int* __restrict__ cursor, int* __restrict__ elist){
  int e = blockIdx.x*256 + threadIdx.x;
  if(e<EE){
    int pos = atomicAdd(&cursor[recv[e]], 1);
    elist[pos] = e;
  }
}

// ---------------- LayerNorm: fp32 in -> bf16 out ----------------
__global__ __launch_bounds__(256) void k_ln_f2b(const float* __restrict__ x,
    const float* __restrict__ sc, const float* __restrict__ of,
    unsigned short* __restrict__ out){
  int gw = (blockIdx.x*256 + threadIdx.x)>>6;
  int lane = threadIdx.x & 63;
  size_t base = (size_t)gw*DD + lane*4;
  float4 xv = *reinterpret_cast<const float4*>(x + base);
  float v[4] = {xv.x, xv.y, xv.z, xv.w};
  float s = v[0]+v[1]+v[2]+v[3];
  float q = v[0]*v[0]+v[1]*v[1]+v[2]*v[2]+v[3]*v[3];
#pragma unroll
  for(int o=32;o>0;o>>=1){ s += __shfl_xor(s,o); q += __shfl_xor(q,o); }
  float mean = s*(1.0f/DD);
  float var = q*(1.0f/DD) - mean*mean;
  float rs = rsqrtf(var + 1e-5f);
  float4 scv = *reinterpret_cast<const float4*>(sc + lane*4);
  float4 ofv = *reinterpret_cast<const float4*>(of + lane*4);
  ushort4 o4;
  o4.x = f2bfu((v[0]-mean)*rs*scv.x+ofv.x);
  o4.y = f2bfu((v[1]-mean)*rs*scv.y+ofv.y);
  o4.z = f2bfu((v[2]-mean)*rs*scv.z+ofv.z);
  o4.w = f2bfu((v[3]-mean)*rs*scv.w+ofv.w);
  *reinterpret_cast<ushort4*>(out + base) = o4;
}

// out = LN(nodes + attn_total), fp32 out
__global__ __launch_bounds__(256) void k_final(
    const float* __restrict__ nodes, const float* __restrict__ attn,
    const float* __restrict__ sc, const float* __restrict__ of,
    float* __restrict__ out){
  int gw = (blockIdx.x*256 + threadIdx.x)>>6;
  int lane = threadIdx.x & 63;
  size_t base = (size_t)gw*DD + lane*4;
  float4 a4 = *reinterpret_cast<const float4*>(nodes + base);
  float4 c4 = *reinterpret_cast<const float4*>(attn + base);
  float v[4];
  v[0]=a4.x+c4.x; v[1]=a4.y+c4.y; v[2]=a4.z+c4.z; v[3]=a4.w+c4.w;
  float s = v[0]+v[1]+v[2]+v[3];
  float q = v[0]*v[0]+v[1]*v[1]+v[2]*v[2]+v[3]*v[3];
#pragma unroll
  for(int o=32;o>0;o>>=1){ s += __shfl_xor(s,o); q += __shfl_xor(q,o); }
  float mean = s*(1.0f/DD);
  float var = q*(1.0f/DD) - mean*mean;
  float rs = rsqrtf(var + 1e-5f);
  float4 scv = *reinterpret_cast<const float4*>(sc + lane*4);
  float4 ofv = *reinterpret_cast<const float4*>(of + lane*4);
  float4 o4;
  o4.x = (v[0]-mean)*rs*scv.x+ofv.x;
  o4.y = (v[1]-mean)*rs*scv.y+ofv.y;
  o4.z = (v[2]-mean)*rs*scv.z+ofv.z;
  o4.w = (v[3]-mean)*rs*scv.w+ofv.w;
  *reinterpret_cast<float4*>(out + base) = o4;
}

// ---------------- Weight transpose + fp32->bf16: in[R][C] f32 -> out[C][R] bf16 ----------------
__global__ void k_transpose(const float* __restrict__ in, unsigned short* __restrict__ out,
                            int R, int C){
  __shared__ unsigned short tile[32][33];
  int c0 = blockIdx.x*32, r0 = blockIdx.y*32;
  int tx = threadIdx.x & 31, ty = threadIdx.x >> 5;
  for(int i=ty;i<32;i+=8){
    int r = r0+i, c = c0+tx;
    tile[i][tx] = (r<R && c<C) ? f2bfu(in[(size_t)r*C + c]) : (unsigned short)0;
  }
  __syncthreads();
  for(int i=ty;i<32;i+=8){
    int c = c0+i, r = r0+tx;
    if(c<C && r<R) out[(size_t)c*R + r] = tile[tx][i];
  }
}

// ---------------- Build fused per-pass projection weights (1 head per pass) ----------------
// WTall[p][c][k]: c in [0,160): g=c>>5 in {Aq,Bq,Ak,Bk,V}, j=c&31; col = p*32+j.
__global__ void k_buildw(const float* __restrict__ Wq, const float* __restrict__ Wk,
                         const float* __restrict__ Wv,
                         const float* __restrict__ bq, const float* __restrict__ bk,
                         const float* __restrict__ bv,
                         unsigned short* __restrict__ WTall, float* __restrict__ biasall){
  int bx = blockIdx.x;            // p*160 + c
  int p = bx/160, c = bx - p*160;
  int k = threadIdx.x;
  int g = c>>5, j = c&31;
  int col = p*32 + j;
  float w;
  if(g==0)      w = Wq[(size_t)k*256 + col];
  else if(g==1) w = Wq[(size_t)(256+k)*256 + col];
  else if(g==2) w = Wk[(size_t)k*256 + col];
  else if(g==3) w = Wk[(size_t)(256+k)*256 + col];
  else          w = Wv[(size_t)k*256 + col];
  WTall[((size_t)bx)*256 + k] = f2bfu(w);
  if(k==0){
    float b = 0.f;
    if(g==0) b = bq[col];
    else if(g==2) b = bk[col];
    else if(g==4) b = bv[col];
    biasall[bx] = b;
  }
}

// ---------------- Projection GEMM: P[ROWS][160] = nnorm @ Bt^T + bias ----------------
// Single column-block (N=160 fully in LDS) so the A panel is read exactly once per pass.
// grid (ROWS/128). 4 waves: wrow=(wid&1)*64, wcol=(wid>>1)*80; wave tile 64x80.
__global__ __launch_bounds__(256) void k_projg(
    const unsigned short* __restrict__ A,      // [ROWS][256]
    const unsigned short* __restrict__ Bt,     // [160][256] for this pass
    const float* __restrict__ bias,            // [160]
    unsigned short* __restrict__ Pout){
  __shared__ unsigned short Asm[128*32];
  __shared__ unsigned short Bsm[160*32];
  int tid = threadIdx.x, lane = tid&63;
  int wid = tid>>6;
  int wrow = (wid&1)*64, wcol = (wid>>1)*80;
  int m0 = blockIdx.x*128;
  f4v acc[4][5];
#pragma unroll
  for(int mi=0;mi<4;mi++)
#pragma unroll
    for(int ni=0;ni<5;ni++) acc[mi][ni] = (f4v){0.f,0.f,0.f,0.f};
  int q = lane>>4, l16 = lane&15;
  int ra0 = tid>>2, ca0 = (tid&3)*8;
  int t1 = tid+256, ra1 = t1>>2, ca1 = (t1&3)*8;
  int t2 = tid+512, ra2 = t2>>2, ca2 = (t2&3)*8;
  for(int k0=0;k0<256;k0+=32){
    glds16(A + (size_t)(m0+ra0)*256 + k0 + ca0, &Asm[tid*8]);
    glds16(A + (size_t)(m0+ra1)*256 + k0 + ca1, &Asm[t1*8]);
    glds16(Bt + (size_t)ra0*256 + k0 + ca0, &Bsm[tid*8]);
    glds16(Bt + (size_t)ra1*256 + k0 + ca1, &Bsm[t1*8]);
    if(tid<128) glds16(Bt + (size_t)ra2*256 + k0 + ca2, &Bsm[t2*8]);
    __syncthreads();
    s8v af[4], bfr[5];
#pragma unroll
    for(int mi=0;mi<4;mi++) af[mi]  = *reinterpret_cast<const s8v*>(&Asm[(wrow+mi*16+l16)*32 + q*8]);
#pragma unroll
    for(int ni=0;ni<5;ni++) bfr[ni] = *reinterpret_cast<const s8v*>(&Bsm[(wcol+ni*16+l16)*32 + q*8]);
#pragma unroll
    for(int mi=0;mi<4;mi++)
#pragma unroll
      for(int ni=0;ni<5;ni++)
        acc[mi][ni] = __builtin_amdgcn_mfma_f32_16x16x32_bf16(af[mi], bfr[ni], acc[mi][ni], 0, 0, 0);
    __syncthreads();
  }
#pragma unroll
  for(int mi=0;mi<4;mi++)
#pragma unroll
    for(int ni=0;ni<5;ni++){
      int ccol = wcol + ni*16 + l16;
      float bvv = bias[ccol];
#pragma unroll
      for(int r=0;r<4;r++){
        int crow = m0 + wrow + mi*16 + q*4 + r;
        Pout[(size_t)crow*PS + ccol] = f2bfu(acc[mi][ni][r] + bvv);
      }
    }
}

// ---------------- Attention phase 1: edge-parallel denominators + exp-tile store ----------------
// One wave per edge (elist order -> consecutive blocks share the receiver, L2-warm bias reads).
// Alibi is dropped: it is constant across edges within a segment, so it cancels exactly in
// the segment softmax (w = exp(S/sqrt(K))/Sum exp). Computes S, accumulates D atomically over
// causal positions, and stores exp(S/sqrt(K)) (bf16, A-fragment layout via LDS transpose) to
// Ebuf so phase 2 never re-gathers Q/K or recomputes S. Masked positions store 0.
__global__ __launch_bounds__(64) void k_attn_stats(
    const unsigned short* __restrict__ P,
    const int* __restrict__ elist,
    const int* __restrict__ receivers, const int* __restrict__ senders,
    float* __restrict__ Dbuf, unsigned short* __restrict__ Ebuf){
  __shared__ unsigned short Wt[32*40];
  int lane = threadIdx.x;
  int e = elist[blockIdx.x];
  int q = lane>>4, l16 = lane&15;
  const float rsK = 0.17677669529663687f;   // 1/sqrt(32)

  int n = receivers[e], s = senders[e];
  size_t nb = (size_t)n*TT*PS + q*8;
  size_t sb = (size_t)s*TT*PS + q*8;

  uint4 rA0 = ld16(P + sb + (size_t)l16*PS);            // Aq
  uint4 rA1 = ld16(P + sb + (size_t)(16+l16)*PS);
  uint4 rK0 = ld16(P + sb + 64 + (size_t)l16*PS);       // Ak
  uint4 rK1 = ld16(P + sb + 64 + (size_t)(16+l16)*PS);
  float BqF0[8], BqF1[8], BkF0[8], BkF1[8];
  ld8bf(P + nb + 32 + (size_t)l16*PS,      BqF0);       // Bq
  ld8bf(P + nb + 32 + (size_t)(16+l16)*PS, BqF1);
  ld8bf(P + nb + 96 + (size_t)l16*PS,      BkF0);       // Bk
  ld8bf(P + nb + 96 + (size_t)(16+l16)*PS, BkF1);

  s8v aq0 = addpack(rA0, BqF0), aq1 = addpack(rA1, BqF1);
  s8v bk0 = addpack(rK0, BkF0), bk1 = addpack(rK1, BkF1);
  f4v zero = (f4v){0.f,0.f,0.f,0.f};
  f4v S[2][2];
  S[0][0] = __builtin_amdgcn_mfma_f32_16x16x32_bf16(aq0, bk0, zero, 0,0,0);
  S[0][1] = __builtin_amdgcn_mfma_f32_16x16x32_bf16(aq0, bk1, zero, 0,0,0);
  S[1][0] = __builtin_amdgcn_mfma_f32_16x16x32_bf16(aq1, bk0, zero, 0,0,0);
  S[1][1] = __builtin_amdgcn_mfma_f32_16x16x32_bf16(aq1, bk1, zero, 0,0,0);

  float* Dn = Dbuf + ((size_t)n<<10);
#pragma unroll
  for(int mt=0;mt<2;mt++)
#pragma unroll
    for(int nt=0;nt<2;nt++)
#pragma unroll
      for(int r=0;r<4;r++){
        int row = mt*16+q*4+r, col = nt*16+l16;
        float ev = 0.f;
        if(col<=row){
          ev = __expf(S[mt][nt][r]*rsK);
          unsafeAtomicAdd(&Dn[row*32+col], ev);
        }
        Wt[row*40 + col] = f2bfu(ev);
      }
  __syncthreads();
  unsigned short* Et = Ebuf + ((size_t)e<<10);
  *reinterpret_cast<s8v*>(Et + lane*8)       = *reinterpret_cast<const s8v*>(&Wt[l16*40 + q*8]);
  *reinterpret_cast<s8v*>(Et + 512 + lane*8) = *reinterpret_cast<const s8v*>(&Wt[(16+l16)*40 + q*8]);
}

// ---------------- Attention phase 2: chunk-parallel PV from precomputed exp-tiles ----------------
// One wave per (node, chunk-of-4-edges); node in LOW blockIdx bits (XCD spread — round-4/6
// lesson). Per edge: coalesced Ebuf read (A-frag layout), scale by Dinv (preloaded per wave),
// masked (col>row) positions = 1/deg (reference's uniform softmax over -1e30 logits), V
// staged via double-buffered LDS transpose. No Q/K gathers, no S recompute, no exp.
__global__ __launch_bounds__(64) void k_attn_pv(
    const unsigned short* __restrict__ P,
    const int* __restrict__ offs, const int* __restrict__ elist,
    const int* __restrict__ senders,
    const float* __restrict__ Dbuf, const unsigned short* __restrict__ Ebuf,
    float* __restrict__ attn, int h){
  __shared__ unsigned short Vb[2][32*40];
  int lane = threadIdx.x;
  int bx = blockIdx.x;
  int n = bx & (NN-1);              // node in LOW bits -> uniform XCD spread
  int c0 = bx >> 11;                // chunk slot in [0,8)
  int o0 = offs[n], deg = offs[n+1]-o0;
  if(c0*4 >= deg) return;
  int q = lane>>4, l16 = lane&15;
  int t2v = lane>>1, halfv = lane&1;
  const float invdeg = 1.0f/(float)deg;

  const float* Dn = Dbuf + ((size_t)n<<10);
  float Di0[8], Di1[8];
#pragma unroll
  for(int j=0;j<8;j++){
    float d0 = Dn[l16*32 + q*8 + j];
    float d1 = Dn[(16+l16)*32 + q*8 + j];
    Di0[j] = (d0 > 0.f) ? 1.0f/d0 : 0.f;
    Di1[j] = (d1 > 0.f) ? 1.0f/d1 : 0.f;
  }

  f4v O[2][2];
  f4v zero = (f4v){0.f,0.f,0.f,0.f};
#pragma unroll
  for(int mt=0;mt<2;mt++)
#pragma unroll
    for(int dt=0;dt<2;dt++) O[mt][dt] = zero;

  for(int c=c0; c*4<deg; c+=8){
    int base = o0 + c*4;
    int rem = deg - c*4;
    int cnt = rem > 4 ? 4 : rem;
    int earr[4], sarr[4];
#pragma unroll
    for(int i=0;i<4;i++){
      int idx = base + (i<cnt ? i : cnt-1);
      earr[i] = elist[idx];
      sarr[i] = senders[earr[i]];
    }
    // prefetch edge 0
    const unsigned short* Et = Ebuf + ((size_t)earr[0]<<10);
    uint4 rE0 = ld16(Et + lane*8);
    uint4 rE1 = ld16(Et + 512 + lane*8);
    size_t vb0 = (size_t)sarr[0]*TT*PS + 128 + (size_t)t2v*PS + halfv*16;
    uint4 rVa = ld16(P + vb0);
    uint4 rVb = ld16(P + vb0 + 8);
    for(int i=0;i<cnt;i++){
      int i2 = (i+1<cnt) ? i+1 : i;
      const unsigned short* Et2 = Ebuf + ((size_t)earr[i2]<<10);
      uint4 nE0 = ld16(Et2 + lane*8);
      uint4 nE1 = ld16(Et2 + 512 + lane*8);
      size_t vb2 = (size_t)sarr[i2]*TT*PS + 128 + (size_t)t2v*PS + halfv*16;
      uint4 nVa = ld16(P + vb2);
      uint4 nVb = ld16(P + vb2 + 8);

      // weights: w = exp_tile * Dinv, masked -> 1/deg
      s8v ap0, ap1;
      {
        const unsigned short* e0 = reinterpret_cast<const unsigned short*>(&rE0);
        const unsigned short* e1 = reinterpret_cast<const unsigned short*>(&rE1);
#pragma unroll
        for(int j=0;j<8;j++){
          int col = q*8 + j;
          float w0 = (col <= l16)      ? bfu2f(e0[j])*Di0[j] : invdeg;
          float w1 = (col <= 16+l16)   ? bfu2f(e1[j])*Di1[j] : invdeg;
          ap0[j] = (short)f2bfu(w0);
          ap1[j] = (short)f2bfu(w1);
        }
      }
      int buf = i&1;
      // stage V^T (raw ushort copy)
      {
        const unsigned short* va = reinterpret_cast<const unsigned short*>(&rVa);
        const unsigned short* vv = reinterpret_cast<const unsigned short*>(&rVb);
#pragma unroll
        for(int j=0;j<8;j++){
          Vb[buf][(halfv*16+j)*40 + t2v]   = va[j];
          Vb[buf][(halfv*16+8+j)*40 + t2v] = vv[j];
        }
      }
      s8v bv0 = *reinterpret_cast<const s8v*>(&Vb[buf][(l16)*40 + q*8]);
      s8v bv1 = *reinterpret_cast<const s8v*>(&Vb[buf][(16+l16)*40 + q*8]);
      O[0][0] = __builtin_amdgcn_mfma_f32_16x16x32_bf16(ap0, bv0, O[0][0], 0,0,0);
      O[0][1] = __builtin_amdgcn_mfma_f32_16x16x32_bf16(ap0, bv1, O[0][1], 0,0,0);
      O[1][0] = __builtin_amdgcn_mfma_f32_16x16x32_bf16(ap1, bv0, O[1][0], 0,0,0);
      O[1][1] = __builtin_amdgcn_mfma_f32_16x16x32_bf16(ap1, bv1, O[1][1], 0,0,0);

      rE0=nE0; rE1=nE1; rVa=nVa; rVb=nVb;
    }
  }

#pragma unroll
  for(int mt=0;mt<2;mt++)
#pragma unroll
    for(int dt=0;dt<2;dt++)
#pragma unroll
      for(int r=0;r<4;r++){
        int row = mt*16+q*4+r;
        unsafeAtomicAdd(&attn[((size_t)n*TT + row)*DD + h*KK + dt*16 + l16], O[mt][dt][r]);
      }
}

// ---------------- FFN GEMM (128x128 tiles, async staging) ----------------
__global__ __launch_bounds__(256) void k_gemmL(
    const unsigned short* __restrict__ A, int lda,
    const unsigned short* __restrict__ Bt, int ldb,
    unsigned short* __restrict__ Cbf, float* __restrict__ Cacc, int ldc,
    int K, const float* __restrict__ bias, int act){
  __shared__ unsigned short Asm[128*32];
  __shared__ unsigned short Bsm[128*32];
  int tid = threadIdx.x;
  int lane = tid & 63, wid = tid >> 6;
  int wrow = (wid>>1)*64, wcol = (wid&1)*64;
  int m0 = blockIdx.x*128, n0 = blockIdx.y*128;
  f4v acc[4][4];
#pragma unroll
  for(int mi=0;mi<4;mi++)
#pragma unroll
    for(int ni=0;ni<4;ni++) acc[mi][ni] = (f4v){0.f,0.f,0.f,0.f};
  int q = lane>>4, l16 = lane&15;
  int ra0 = tid>>2, ca0 = (tid&3)*8;
  int c1 = tid+256, ra1 = c1>>2, ca1 = (c1&3)*8;
  for(int k0=0;k0<K;k0+=32){
    glds16(A + (size_t)(m0+ra0)*lda + k0 + ca0, &Asm[tid*8]);
    glds16(A + (size_t)(m0+ra1)*lda + k0 + ca1, &Asm[c1*8]);
    glds16(Bt + (size_t)(n0+ra0)*ldb + k0 + ca0, &Bsm[tid*8]);
    glds16(Bt + (size_t)(n0+ra1)*ldb + k0 + ca1, &Bsm[c1*8]);
    __syncthreads();
    s8v af[4], bfr[4];
#pragma unroll
    for(int mi=0;mi<4;mi++) af[mi]  = *reinterpret_cast<const s8v*>(&Asm[(wrow+mi*16+l16)*32 + q*8]);
#pragma unroll
    for(int ni=0;ni<4;ni++) bfr[ni] = *reinterpret_cast<const s8v*>(&Bsm[(wcol+ni*16+l16)*32 + q*8]);
#pragma unroll
    for(int mi=0;mi<4;mi++)
#pragma unroll
      for(int ni=0;ni<4;ni++)
        acc[mi][ni] = __builtin_amdgcn_mfma_f32_16x16x32_bf16(af[mi], bfr[ni], acc[mi][ni], 0, 0, 0);
    __syncthreads();
  }
#pragma unroll
  for(int mi=0;mi<4;mi++)
#pragma unroll
    for(int ni=0;ni<4;ni++){
      int ccol = n0 + wcol + ni*16 + l16;
      float bv = bias ? bias[ccol] : 0.f;
#pragma unroll
      for(int r=0;r<4;r++){
        int crow = m0 + wrow + mi*16 + q*4 + r;
        float v = acc[mi][ni][r] + bv;
        if(act==1){
          float x = v;
          float z = 0.7978845608028654f*(x + 0.044715f*x*x*x);
          float t = 1.f - 2.f/(__expf(2.f*z) + 1.f);   // tanh(z), overflow-safe
          v = 0.5f*x*(1.f + t);
        }
        if(Cacc) Cacc[(size_t)crow*ldc + ccol] += v;
        else     Cbf[(size_t)crow*ldc + ccol] = f2bfu(v);
      }
    }
}

// ---------------- Orchestration ----------------
extern "C" void kernel_launch(void* const* d_in, const int* in_sizes, int n_in,
                              void* d_out, int out_size, void* d_ws, size_t ws_size,
                              hipStream_t stream) {
  const float* nodes    = (const float*)d_in[0];
  const int*   senders  = (const int*)d_in[1];
  const int*   receivers= (const int*)d_in[2];
  const float* lnq_s    = (const float*)d_in[4];
  const float* lnq_o    = (const float*)d_in[5];
  const float* Wq       = (const float*)d_in[6];
  const float* bq       = (const float*)d_in[7];
  const float* Wk       = (const float*)d_in[8];
  const float* bk       = (const float*)d_in[9];
  const float* Wv       = (const float*)d_in[10];
  const float* bv       = (const float*)d_in[11];
  const float* lnm_s    = (const float*)d_in[12];
  const float* lnm_o    = (const float*)d_in[13];
  const float* W1       = (const float*)d_in[14];
  const float* b1       = (const float*)d_in[15];
  const float* W2       = (const float*)d_in[16];
  const float* b2       = (const float*)d_in[17];
  const float* lno_s    = (const float*)d_in[18];
  const float* lno_o    = (const float*)d_in[19];
  // d_in[3] (alibi) intentionally unused: it cancels exactly in the segment softmax.

  char* ws = (char*)d_ws;
  // layout — end (161150208 B = 153.7 MiB) identical to the proven round-2/4/6 footprint:
  size_t o_nnorm = 0;                         // bf16 ROWS*256 = 33.5 MB ; Xm overlay later
  size_t o_P2    = 33554432;                  // region 33.5 MB: P (21 MB) now; H1c (33.5) later
  size_t o_attn  = 67108864;                  // fp32 ROWS*256 = 67.1 MB
  size_t o_w1t   = 134217728;                 // 1024x256 bf16 = 524288
  size_t o_w2t   = 134742016;                 // 256x1024 bf16 = 524288
  size_t o_wall  = 135266304;                 // 8*160*256 bf16 = 655360
  size_t o_ball  = 135921664;                 // 8*160 fp32 = 5120
  size_t o_dbuf  = 135926784;                 // NN*1024 fp32 = 8,388,608
  size_t o_ebuf  = 144315392;                 // EE*1024 bf16 = 16,777,216
  size_t o_csr   = 161092608;
  size_t o_deg   = o_csr;
  size_t o_offs  = o_csr + 8192;
  size_t o_cur   = o_csr + 16640;
  size_t o_elist = o_csr + 24832;

  unsigned short* nnorm = (unsigned short*)(ws + o_nnorm);
  unsigned short* P2    = (unsigned short*)(ws + o_P2);
  float* attn = (float*)(ws + o_attn);
  unsigned short* w1t   = (unsigned short*)(ws + o_w1t);
  unsigned short* w2t   = (unsigned short*)(ws + o_w2t);
  unsigned short* WTall = (unsigned short*)(ws + o_wall);
  float* biasall = (float*)(ws + o_ball);
  float* Dbuf    = (float*)(ws + o_dbuf);
  unsigned short* Ebuf  = (unsigned short*)(ws + o_ebuf);
  int* deg    = (int*)(ws + o_deg);
  int* offs   = (int*)(ws + o_offs);
  int* cursor = (int*)(ws + o_cur);
  int* elist  = (int*)(ws + o_elist);
  unsigned short* H1c = (unsigned short*)(ws + o_P2);     // overlay (P2 dead after attention)
  unsigned short* Xm  = (unsigned short*)(ws + o_nnorm);  // overlay (nnorm dead after last projg)

  // CSR build
  k_zero_i32<<<8, 256, 0, stream>>>(deg, NN);
  k_hist<<<EE/256, 256, 0, stream>>>(receivers, deg);
  k_scan<<<1, 256, 0, stream>>>(deg, offs, cursor);
  k_scatter<<<EE/256, 256, 0, stream>>>(receivers, cursor, elist);

  // LN(nodes) -> nnorm (bf16)
  k_ln_f2b<<<ROWS/4, 256, 0, stream>>>(nodes, lnq_s, lnq_o, nnorm);

  // weights: W1/W2 transposed (fp32->bf16); fused projection weights (8 passes x 160 cols)
  k_transpose<<<dim3(32,8), 256, 0, stream>>>(W1, w1t, 256, 1024);
  k_transpose<<<dim3(8,32), 256, 0, stream>>>(W2, w2t, 1024, 256);
  k_buildw<<<8*160, 256, 0, stream>>>(Wq, Wk, Wv, bq, bk, bv, WTall, biasall);

  // zero attention accumulator (k_attn_pv atomically accumulates into it)
  k_zero_f4<<<ROWS*DD/1024, 256, 0, stream>>>((float4*)attn, ROWS*DD/4);

  // attention: 8 passes of 1 head
  for(int p=0;p<HH;p++){
    k_zero_f4<<<NN*1024/1024, 256, 0, stream>>>((float4*)Dbuf, NN*1024/4);
    k_projg<<<ROWS/128, 256, 0, stream>>>(nnorm, WTall + (size_t)p*160*256,
                                          biasall + p*160, P2);
    k_attn_stats<<<EE, 64, 0, stream>>>(P2, elist, receivers, senders, Dbuf, Ebuf);
    k_attn_pv<<<NN*8, 64, 0, stream>>>(P2, offs, elist, senders, Dbuf, Ebuf, attn, p);
  }

  // FFN: Xm = LN(attn); 4 row-chunks of 16384: H1c = gelu(Xm@W1+b1); attn += H1c@W2+b2
  k_ln_f2b<<<ROWS/4, 256, 0, stream>>>(attn, lnm_s, lnm_o, Xm);
  for(int cch=0; cch<4; cch++){
    const unsigned short* Xc = Xm + (size_t)cch*16384*256;
    k_gemmL<<<dim3(128, 8), 256, 0, stream>>>(Xc, 256, w1t, 256,
                                              H1c, nullptr, 1024, 256, b1, 1);
    k_gemmL<<<dim3(128, 2), 256, 0, stream>>>(H1c, 1024, w2t, 1024,
                                              nullptr, attn + (size_t)cch*16384*256, 256,
                                              1024, b2, 0);
  }

  // out = LN(nodes + attn)
  k_final<<<ROWS/4, 256, 0, stream>>>(nodes, attn, lno_s, lno_o, (float*)d_out);
}